// Round 6
// baseline (388.492 us; speedup 1.0000x reference)
//
#include <hip/hip_runtime.h>

#define NTAG 128
#define SEQ 512
#define NBATCH 512
#define END_ID 1

typedef _Float16 h2 __attribute__((ext_vector_type(2)));
typedef __fp16 fp16x2 __attribute__((ext_vector_type(2)));
typedef uint u32x32 __attribute__((ext_vector_type(32)));

#define LOG2E 1.4426950408889634f
#define LN2   0.6931471805599453f

__device__ __forceinline__ float bcast0(float v) {
  return __int_as_float(__builtin_amdgcn_readfirstlane(__float_as_int(v)));
}
__device__ __forceinline__ uint pack2(float a, float b) {
  fp16x2 h = __builtin_amdgcn_cvt_pkrtz(a, b);
  return __builtin_bit_cast(uint, h);
}
__device__ __forceinline__ h2 as_h2(uint u) { return __builtin_bit_cast(h2, u); }

__device__ __forceinline__ float fast_exp2(float x) {
#if __has_builtin(__builtin_amdgcn_exp2f)
  return __builtin_amdgcn_exp2f(x);
#else
  return exp2f(x);
#endif
}
__device__ __forceinline__ float fast_log2(float x) {
#if __has_builtin(__builtin_amdgcn_logf)
  return __builtin_amdgcn_logf(x);
#else
  return log2f(x);
#endif
}

#if __has_builtin(__builtin_amdgcn_fdot2)
#define FDOT2(pu, eu, acc) acc = __builtin_amdgcn_fdot2(as_h2(pu), as_h2(eu), acc, false)
#else
#define FDOT2(pu, eu, acc) do { h2 _p = as_h2(pu), _e = as_h2(eu); \
  acc = fmaf((float)_p.x, (float)_e.x, fmaf((float)_p.y, (float)_e.y, acc)); } while (0)
#endif

#define RL(v, l) ((uint)__builtin_amdgcn_readlane((int)(v), (l)))
#define EL(c) ((c) < 32 ? eL0[(c)] : eL1[(c) - 32])
#define EH(c) ((c) < 32 ? eH0[(c)] : eH1[(c) - 32])

// One WAVE per batch; lane l owns tags 2l, 2l+1. E' = exp2(trans*log2e) as
// f16 pairs in 128 regs. Per-step all-to-all of p via v_readlane -> SGPR ->
// dot2 SGPR-source. Round-5 lesson: at 1 wave/SIMD every dependency stall is
// exposed -> (a) EIGHT accumulator chains (depth 16 each, hidden under
// 2-cyc issue), (b) readlanes batched 8-ahead into distinct SGPRs so the
// VALU-write-SGPR -> VALU-read hazard windows are covered by other work.
// Recurrence in log2 domain (v_exp/v_log are base-2 natively). Shift
// M = A[tag0]: spread <= ~15 log2-units => p < 2^15 < f16 max (clamped).
__global__ __launch_bounds__(64, 1) void crf_kernel(
    const float* __restrict__ x,      // [B,S,T]
    const int*   __restrict__ tags,   // [B,S]
    const float* __restrict__ mask,   // [B,S]
    const float* __restrict__ trans,  // [T,T]
    float* __restrict__ ws)           // [B]
{
  const int b    = blockIdx.x;
  const int lane = threadIdx.x;       // 0..63

  const float* xb   = x    + (size_t)b * SEQ * NTAG;
  const float* mrow = mask + (size_t)b * SEQ;
  const int*   trow = tags + (size_t)b * SEQ;

  // ---- len = sum(mask row); mask is exact 0.0/1.0, monotonic ----
  float msum = 0.f;
  #pragma unroll
  for (int i = 0; i < SEQ / 64; ++i) msum += mrow[lane + i * 64];
  #pragma unroll
  for (int off = 1; off < 64; off <<= 1) msum += __shfl_xor(msum, off);
  const int len = (int)msum;          // in [1, 510]

  // ---- E' rows 2l (L) and 2l+1 (H): exp2(T*log2e), f16-paired ----
  u32x32 eL0, eL1, eH0, eH1;          // pair kp: [kp<32 ? *0 : *1][kp&31]
  {
    const float4* r0 = (const float4*)(trans + (size_t)(2 * lane) * NTAG);
    const float4* r1 = (const float4*)(trans + (size_t)(2 * lane + 1) * NTAG);
    #pragma unroll
    for (int k4 = 0; k4 < 16; ++k4) {
      float4 lo = r0[k4], hi = r1[k4];
      eL0[2 * k4 + 0] = pack2(fast_exp2(lo.x * LOG2E), fast_exp2(lo.y * LOG2E));
      eL0[2 * k4 + 1] = pack2(fast_exp2(lo.z * LOG2E), fast_exp2(lo.w * LOG2E));
      eH0[2 * k4 + 0] = pack2(fast_exp2(hi.x * LOG2E), fast_exp2(hi.y * LOG2E));
      eH0[2 * k4 + 1] = pack2(fast_exp2(hi.z * LOG2E), fast_exp2(hi.w * LOG2E));
    }
    #pragma unroll
    for (int k4 = 16; k4 < 32; ++k4) {
      float4 lo = r0[k4], hi = r1[k4];
      eL1[2 * (k4 - 16) + 0] = pack2(fast_exp2(lo.x * LOG2E), fast_exp2(lo.y * LOG2E));
      eL1[2 * (k4 - 16) + 1] = pack2(fast_exp2(lo.z * LOG2E), fast_exp2(lo.w * LOG2E));
      eH1[2 * (k4 - 16) + 0] = pack2(fast_exp2(hi.x * LOG2E), fast_exp2(hi.y * LOG2E));
      eH1[2 * (k4 - 16) + 1] = pack2(fast_exp2(hi.z * LOG2E), fast_exp2(hi.w * LOG2E));
    }
  }

  // log2-domain alpha
  float A_lo = (lane == 0) ? 0.f : -14427.f;   // -1e4 * log2e  (START_ID=0)
  float A_hi = -14427.f;
  float2 xt = ((const float2*)xb)[lane];       // x[b][0][2l..2l+1]

  for (int t = 0; t < len; ++t) {
    const float M = bcast0(A_lo);              // A[tag 0], SGPR broadcast
    const uint pk = pack2(fminf(fast_exp2(A_lo - M), 60000.f),
                          fminf(fast_exp2(A_hi - M), 60000.f));

    // prefetch next emission (t+1 <= len <= 510 < SEQ), coalesced float2
    const float2 xn = ((const float2*)(xb + (size_t)(t + 1) * NTAG))[lane];

    float qL0 = 0.f, qL1 = 0.f, qL2 = 0.f, qL3 = 0.f;
    float qH0 = 0.f, qH1 = 0.f, qH2 = 0.f, qH3 = 0.f;
    #pragma unroll
    for (int g = 0; g < 64; g += 8) {
      // batch 8 readlanes ahead (8 distinct SGPRs) to bury the
      // VALU-writes-SGPR -> VALU-reads-SGPR hazard
      const uint s0 = RL(pk, g + 0), s1 = RL(pk, g + 1);
      const uint s2 = RL(pk, g + 2), s3 = RL(pk, g + 3);
      const uint s4 = RL(pk, g + 4), s5 = RL(pk, g + 5);
      const uint s6 = RL(pk, g + 6), s7 = RL(pk, g + 7);
      FDOT2(s0, EL(g + 0), qL0); FDOT2(s0, EH(g + 0), qH0);
      FDOT2(s1, EL(g + 1), qL1); FDOT2(s1, EH(g + 1), qH1);
      FDOT2(s2, EL(g + 2), qL2); FDOT2(s2, EH(g + 2), qH2);
      FDOT2(s3, EL(g + 3), qL3); FDOT2(s3, EH(g + 3), qH3);
      FDOT2(s4, EL(g + 4), qL0); FDOT2(s4, EH(g + 4), qH0);
      FDOT2(s5, EL(g + 5), qL1); FDOT2(s5, EH(g + 5), qH1);
      FDOT2(s6, EL(g + 6), qL2); FDOT2(s6, EH(g + 6), qH2);
      FDOT2(s7, EL(g + 7), qL3); FDOT2(s7, EH(g + 7), qH3);
    }
    const float qL = (qL0 + qL1) + (qL2 + qL3);
    const float qH = (qH0 + qH1) + (qH2 + qH3);

    A_lo = fmaf(xt.x, LOG2E, M + fast_log2(qL));
    A_hi = fmaf(xt.y, LOG2E, M + fast_log2(qH));
    xt = xn;
  }

  // back to natural-log domain
  const float a_lo = A_lo * LN2;
  const float a_hi = A_hi * LN2;

  // ---- fwd = logsumexp_j(alpha[j] + trans[END][j]) (exact max, once) ----
  const float2 te = ((const float2*)(trans + END_ID * NTAG))[lane];
  const float v_lo = a_lo + te.x;
  const float v_hi = a_hi + te.y;
  float m2 = fmaxf(v_lo, v_hi);
  #pragma unroll
  for (int off = 1; off < 64; off <<= 1) m2 = fmaxf(m2, __shfl_xor(m2, off));
  float s = fast_exp2((v_lo - m2) * LOG2E) + fast_exp2((v_hi - m2) * LOG2E);
  #pragma unroll
  for (int off = 1; off < 64; off <<= 1) s += __shfl_xor(s, off);
  const float fwd = m2 + fast_log2(s) * LN2;

  // ---- gold score ----
  float g = 0.f;
  for (int i = lane; i < len; i += 64) {
    const int tn = trow[i + 1];
    const int tp = trow[i];
    g += xb[(size_t)i * NTAG + tn] + trans[tn * NTAG + tp];
  }
  #pragma unroll
  for (int off = 1; off < 64; off <<= 1) g += __shfl_xor(g, off);

  if (lane == 0) {
    const float gold = g + trans[END_ID * NTAG + trow[len]];
    ws[b] = fwd - gold;
  }
}

__global__ void reduce_kernel(const float* __restrict__ ws, float* __restrict__ out) {
  __shared__ float sm[8];
  const int tid = threadIdx.x;   // 512
  float v = ws[tid];
  #pragma unroll
  for (int off = 1; off < 64; off <<= 1) v += __shfl_xor(v, off);
  if ((tid & 63) == 0) sm[tid >> 6] = v;
  __syncthreads();
  if (tid == 0) {
    float s = 0.f;
    #pragma unroll
    for (int w = 0; w < 8; ++w) s += sm[w];
    out[0] = s * (1.0f / 512.0f);
  }
}

extern "C" void kernel_launch(void* const* d_in, const int* in_sizes, int n_in,
                              void* d_out, int out_size, void* d_ws, size_t ws_size,
                              hipStream_t stream) {
  const float* x     = (const float*)d_in[0];
  const int*   tags  = (const int*)d_in[1];
  const float* mask  = (const float*)d_in[2];
  const float* trans = (const float*)d_in[3];
  float*       ws    = (float*)d_ws;

  crf_kernel<<<NBATCH, 64, 0, stream>>>(x, tags, mask, trans, ws);
  reduce_kernel<<<1, 512, 0, stream>>>(ws, (float*)d_out);
}